// Round 11
// baseline (872.443 us; speedup 1.0000x reference)
//
#include <hip/hip_runtime.h>

#define NN 100000
#define En 400000
#define Gn 2000
#define GRID 2048

typedef unsigned short u16;
typedef unsigned int u32;
typedef _Float16 f16;
typedef f16 f16x8 __attribute__((ext_vector_type(8)));
typedef f16 f16x4 __attribute__((ext_vector_type(4)));
typedef float f32x4 __attribute__((ext_vector_type(4)));

// barrier that drains only LDS ops (global loads/atomics stay in flight)
__device__ __forceinline__ void lds_barrier() {
  asm volatile("s_waitcnt lgkmcnt(0)\ns_barrier" ::: "memory");
}

#define MFMA16(a, b, c) __builtin_amdgcn_mfma_f32_16x16x32_f16(a, b, c, 0, 0, 0)

// ---------------- fused weight prep: converts + pads + hist zero ----------------

__global__ __launch_bounds__(256) void k_prepw(
    const float* __restrict__ Wn1, const float* __restrict__ Wn2,
    const float* __restrict__ Wc, const float* __restrict__ We2,
    const float* __restrict__ We1,
    f16* __restrict__ Wn1b, f16* __restrict__ Wn2b, f16* __restrict__ Wcb,
    f16* __restrict__ We2b, f16* __restrict__ Rb, u32* __restrict__ hist) {
  int i = blockIdx.x * 256 + threadIdx.x;
  if (i < 49152) {
    Wn1b[i] = (f16)Wn1[i];
  } else if (i < 98304) {
    int j = i - 49152;
    Wn2b[j] = (f16)Wn2[j];
  } else if (i < 147456) {
    int j = i - 98304;
    Wcb[j] = (f16)Wc[j];
  } else if (i < 319488) {
    int j = i - 147456;
    int l = j / 57344;
    int r = j - l * 57344;
    int row = r / 448;
    int k = r - row * 448;
    float v = (k < 428) ? We2[l * 54784 + row * 428 + k] : 0.f;
    We2b[j] = (f16)v;
  } else if (i < 749568) {
    int j = i - 319488;
    int l = j / 143360;
    int r = j - l * 143360;
    int row = r / 320;
    int k = r - row * 320;
    float v = 0.f;
    if (row < 428 && k < 300) v = We1[(size_t)l * 183184 + row * 428 + 128 + k];
    Rb[j] = (f16)v;
  } else if (i < 849568) {
    hist[i - 749568] = 0u;  // folded k_zero32
  }
}

// ---------------- T2 via MFMA ----------------
// T2[l][t][j] = edge_emb[t]·We1[l][j][:128] + be1[l][j]   f16 [3][400][448]

__global__ __launch_bounds__(256) void k_t2(const float* __restrict__ edge_emb,
                                            const float* __restrict__ We1,
                                            const float* __restrict__ be1,
                                            f16* __restrict__ T2) {
  __shared__ __align__(16) f16 sA[64 * 136];
  __shared__ __align__(16) f16 sB[128 * 136];
  const int tid = threadIdx.x;
  const int l = blockIdx.x / 28;
  const int rb = blockIdx.x - l * 28;
  const int tb = rb >> 2, jb = rb & 3;
  const int t0 = tb * 64, j0 = jb * 128;
  for (int i = tid; i < 64 * 32; i += 256) {
    int e = i >> 5, c = (i & 31) * 4;
    int t = t0 + e;
    float4 v = make_float4(0.f, 0.f, 0.f, 0.f);
    if (t < 400) v = *(const float4*)&edge_emb[t * 128 + c];
    f16x4 o = {(f16)v.x, (f16)v.y, (f16)v.z, (f16)v.w};
    *(f16x4*)&sA[e * 136 + c] = o;
  }
  for (int i = tid; i < 128 * 32; i += 256) {
    int rr = i >> 5, c = (i & 31) * 4;
    int j = j0 + rr;
    float4 v = make_float4(0.f, 0.f, 0.f, 0.f);
    if (j < 428) v = *(const float4*)&We1[(size_t)l * 183184 + j * 428 + c];
    f16x4 o = {(f16)v.x, (f16)v.y, (f16)v.z, (f16)v.w};
    *(f16x4*)&sB[rr * 136 + c] = o;
  }
  lds_barrier();
  const int lane = tid & 63, wave = tid >> 6;
  const int q = lane >> 4, ln = lane & 15;
  const int nb = wave * 32;

  f32x4 acc[4][2];
#pragma unroll
  for (int m = 0; m < 4; ++m)
#pragma unroll
    for (int n = 0; n < 2; ++n) acc[m][n] = 0.f;
#pragma unroll
  for (int k0 = 0; k0 < 128; k0 += 32) {
    f16x8 a[4];
#pragma unroll
    for (int m = 0; m < 4; ++m)
      a[m] = *(const f16x8*)&sA[(m * 16 + ln) * 136 + k0 + q * 8];
#pragma unroll
    for (int n = 0; n < 2; ++n) {
      f16x8 b = *(const f16x8*)&sB[(nb + n * 16 + ln) * 136 + k0 + q * 8];
#pragma unroll
      for (int m = 0; m < 4; ++m) acc[m][n] = MFMA16(a[m], b, acc[m][n]);
    }
  }
#pragma unroll
  for (int n = 0; n < 2; ++n) {
    int col = nb + n * 16 + ln;
    int gj = j0 + col;
    float bb = (gj < 428) ? be1[l * 428 + gj] : 0.f;
#pragma unroll
    for (int m = 0; m < 4; ++m)
#pragma unroll
      for (int r = 0; r < 4; ++r) {
        int row = m * 16 + q * 4 + r;
        int t = t0 + row;
        if (t < 400 && gj < 448) {
          float s = acc[m][n][r] + bb;
          T2[l * 179200 + t * 448 + gj] = (gj < 428) ? (f16)s : (f16)0.f;
        }
      }
  }
}

// Dtab[l][g][j] = sum_k rbf_k(g*delta) * R[l][j][k]   f16 [3][GRID+1][448]
// Vectorized: 5x f16x8 loads over an 8-aligned 40-tap window (vs 32 scalar
// f16 loads). Excluded far taps have weight <= exp(-25) ~ 1e-11.
__global__ __launch_bounds__(256) void k_dtab(const f16* __restrict__ Rb,
                                              f16* __restrict__ Dtab) {
  const int tid = threadIdx.x;
  int l = blockIdx.x / (GRID + 1);
  int g = blockIdx.x - l * (GRID + 1);
  float d = (float)g * (30.f / (float)GRID);
  int kc = (int)(d * (299.f / 30.f) + 0.5f);
  int kk0 = min(max(kc - 20, 0), 280) & ~7;
  __shared__ float sE[40];
  if (tid < 40) {
    float x = d - (float)(kk0 + tid) * (30.f / 299.f);
    sE[tid] = __expf(-x * x * (299.f / 30.f));
  }
  __syncthreads();
  for (int j = tid; j < 448; j += 256) {
    const f16* rr = &Rb[((size_t)l * 448 + j) * 320 + kk0];
    float s = 0.f;
#pragma unroll
    for (int v = 0; v < 5; ++v) {
      f16x8 rv = *(const f16x8*)&rr[v * 8];
#pragma unroll
      for (int t = 0; t < 8; ++t) s += sE[v * 8 + t] * (float)rv[t];
    }
    Dtab[((size_t)(l * (GRID + 1) + g)) * 448 + j] = (f16)s;
  }
}

// ---------------- counting sort of edges by dst ----------------

__global__ __launch_bounds__(256) void k_hist(const int* __restrict__ dstv,
                                              u32* __restrict__ hist) {
  int e = blockIdx.x * 256 + threadIdx.x;
  if (e < En) atomicAdd(&hist[dstv[e]], 1u);
}

// shfl-based block scan (2 barriers vs 20)
__global__ __launch_bounds__(1024) void k_scan1(const u32* __restrict__ hist,
                                                u32* __restrict__ excl,
                                                u32* __restrict__ part) {
  __shared__ u32 ws[16];
  const int t = threadIdx.x, b = blockIdx.x, i = b * 1024 + t;
  const int lane = t & 63, wid = t >> 6;
  u32 v = (i < NN) ? hist[i] : 0u;
  u32 acc = v;
#pragma unroll
  for (int off = 1; off < 64; off <<= 1) {
    u32 x = __shfl_up(acc, off);
    if (lane >= off) acc += x;
  }
  if (lane == 63) ws[wid] = acc;
  __syncthreads();
  if (t < 16) {
    u32 wa = ws[t];
#pragma unroll
    for (int off = 1; off < 16; off <<= 1) {
      u32 x = __shfl_up(wa, off);
      if (t >= off) wa += x;
    }
    ws[t] = wa;
  }
  __syncthreads();
  u32 base = (wid > 0) ? ws[wid - 1] : 0u;
  u32 inc = base + acc;
  if (i < NN) excl[i] = inc - v;
  if (t == 1023) part[b] = inc;
}

// scan3 with scan2 folded in: each block reduces part[0..b-1] itself
// (<=97 values, ~100 extra ops per block) -> one fewer kernel launch.
__global__ __launch_bounds__(1024) void k_scan3(const u32* __restrict__ excl,
                                                const u32* __restrict__ part,
                                                u32* __restrict__ cursor) {
  __shared__ u32 sW[2];
  __shared__ u32 sBase;
  const int t = threadIdx.x, b = blockIdx.x;
  if (t < 128) {
    u32 v = (t < b) ? part[t] : 0u;  // b <= 97 < 128
#pragma unroll
    for (int off = 32; off > 0; off >>= 1) v += __shfl_down(v, off);
    if ((t & 63) == 0) sW[t >> 6] = v;
  }
  __syncthreads();
  if (t == 0) sBase = sW[0] + sW[1];
  __syncthreads();
  int i = b * 1024 + t;
  if (i < NN) cursor[i] = excl[i] + sBase;
}

// nearest-bin index (r8); dst packed into epack.w (edst array eliminated).
// fi < 2048 -> round(fi) <= 2048; Dtab has GRID+1 = 2049 rows -> in range.
__global__ __launch_bounds__(256) void k_scatter(const int* __restrict__ etype,
                                                 const float* __restrict__ dist,
                                                 const int* __restrict__ srcv,
                                                 const int* __restrict__ dstv,
                                                 u32* __restrict__ cursor,
                                                 int4* __restrict__ epack) {
  int e = blockIdx.x * 256 + threadIdx.x;
  if (e >= En) return;
  int d = dstv[e];
  int pos = (int)atomicAdd(&cursor[d], 1u);
  float fi = dist[e] * ((float)GRID / 30.f);
  int ix = (int)(fi + 0.5f);
  epack[pos] = make_int4(srcv[e], etype[e] * 448, ix * 448, d);
}

// ---------------- node MLP: n2 = relu(h@W1^T+b1)@W2^T+b2  (f16 out) ----------------

__global__ __launch_bounds__(256) void k_node(const float* __restrict__ h,
                                              const f16* __restrict__ W1,
                                              const float* __restrict__ b1,
                                              const f16* __restrict__ W2,
                                              const float* __restrict__ b2,
                                              f16* __restrict__ n2) {
  __shared__ __align__(16) f16 sH[64 * 136];
  __shared__ __align__(16) f16 sT[64 * 136];
  const int tid = threadIdx.x;
  const int nbase = blockIdx.x * 64;
  for (int i = tid; i < 64 * 32; i += 256) {
    int e = i >> 5, c = (i & 31) * 4;
    int node = nbase + e;
    float4 v = make_float4(0.f, 0.f, 0.f, 0.f);
    if (node < NN) v = *(const float4*)&h[(size_t)node * 128 + c];
    f16x4 o = {(f16)v.x, (f16)v.y, (f16)v.z, (f16)v.w};
    *(f16x4*)&sH[e * 136 + c] = o;
  }
  lds_barrier();
  const int lane = tid & 63, wave = tid >> 6;
  const int q = lane >> 4, ln = lane & 15;
  const int nb = wave * 32;

  f32x4 acc[4][2];
#pragma unroll
  for (int m = 0; m < 4; ++m)
#pragma unroll
    for (int n = 0; n < 2; ++n) acc[m][n] = 0.f;
#pragma unroll
  for (int k0 = 0; k0 < 128; k0 += 32) {
    f16x8 a[4];
#pragma unroll
    for (int m = 0; m < 4; ++m)
      a[m] = *(const f16x8*)&sH[(m * 16 + ln) * 136 + k0 + q * 8];
#pragma unroll
    for (int n = 0; n < 2; ++n) {
      f16x8 b = *(const f16x8*)&W1[(nb + n * 16 + ln) * 128 + k0 + q * 8];
#pragma unroll
      for (int m = 0; m < 4; ++m) acc[m][n] = MFMA16(a[m], b, acc[m][n]);
    }
  }
#pragma unroll
  for (int n = 0; n < 2; ++n) {
    int col = nb + n * 16 + ln;
    float bb = b1[col];
#pragma unroll
    for (int m = 0; m < 4; ++m)
#pragma unroll
      for (int r = 0; r < 4; ++r) {
        int row = m * 16 + q * 4 + r;
        sT[row * 136 + col] = (f16)fmaxf(acc[m][n][r] + bb, 0.f);
      }
  }
  lds_barrier();

  f32x4 acc2[4][2];
#pragma unroll
  for (int m = 0; m < 4; ++m)
#pragma unroll
    for (int n = 0; n < 2; ++n) acc2[m][n] = 0.f;
#pragma unroll
  for (int k0 = 0; k0 < 128; k0 += 32) {
    f16x8 a[4];
#pragma unroll
    for (int m = 0; m < 4; ++m)
      a[m] = *(const f16x8*)&sT[(m * 16 + ln) * 136 + k0 + q * 8];
#pragma unroll
    for (int n = 0; n < 2; ++n) {
      f16x8 b = *(const f16x8*)&W2[(nb + n * 16 + ln) * 128 + k0 + q * 8];
#pragma unroll
      for (int m = 0; m < 4; ++m) acc2[m][n] = MFMA16(a[m], b, acc2[m][n]);
    }
  }
#pragma unroll
  for (int n = 0; n < 2; ++n) {
    int col = nb + n * 16 + ln;
    float bb = b2[col];
#pragma unroll
    for (int m = 0; m < 4; ++m)
#pragma unroll
      for (int r = 0; r < 4; ++r) {
        int row = m * 16 + q * 4 + r;
        int node = nbase + row;
        if (node < NN) n2[(size_t)node * 128 + col] = (f16)(acc2[m][n][r] + bb);
      }
  }
}

// ---------------- layer-0 node MLP fused with h-init ----------------

__global__ __launch_bounds__(256) void k_node0(const int* __restrict__ Z,
                                               const float* __restrict__ node_emb,
                                               const f16* __restrict__ W1,
                                               const float* __restrict__ b1,
                                               const f16* __restrict__ W2,
                                               const float* __restrict__ b2,
                                               f16* __restrict__ n2,
                                               float* __restrict__ h,
                                               float* __restrict__ out) {
  __shared__ __align__(16) f16 sH[64 * 136];
  __shared__ __align__(16) f16 sT[64 * 136];
  __shared__ int sZ[64];
  const int tid = threadIdx.x;
  const int nbase = blockIdx.x * 64;
  {
    int oi = blockIdx.x * 256 + tid;
    if (oi < Gn) out[oi] = 0.f;
  }
  if (tid < 64) sZ[tid] = Z[min(nbase + tid, NN - 1)];
  lds_barrier();
  for (int i = tid; i < 64 * 32; i += 256) {
    int e = i >> 5, c = (i & 31) * 4;
    int node = nbase + e;
    float4 v = *(const float4*)&node_emb[sZ[e] * 128 + c];
    f16x4 o = {(f16)v.x, (f16)v.y, (f16)v.z, (f16)v.w};
    *(f16x4*)&sH[e * 136 + c] = o;
    if (node < NN) *(float4*)&h[(size_t)node * 128 + c] = v;
  }
  lds_barrier();
  const int lane = tid & 63, wave = tid >> 6;
  const int q = lane >> 4, ln = lane & 15;
  const int nb = wave * 32;

  f32x4 acc[4][2];
#pragma unroll
  for (int m = 0; m < 4; ++m)
#pragma unroll
    for (int n = 0; n < 2; ++n) acc[m][n] = 0.f;
#pragma unroll
  for (int k0 = 0; k0 < 128; k0 += 32) {
    f16x8 a[4];
#pragma unroll
    for (int m = 0; m < 4; ++m)
      a[m] = *(const f16x8*)&sH[(m * 16 + ln) * 136 + k0 + q * 8];
#pragma unroll
    for (int n = 0; n < 2; ++n) {
      f16x8 b = *(const f16x8*)&W1[(nb + n * 16 + ln) * 128 + k0 + q * 8];
#pragma unroll
      for (int m = 0; m < 4; ++m) acc[m][n] = MFMA16(a[m], b, acc[m][n]);
    }
  }
#pragma unroll
  for (int n = 0; n < 2; ++n) {
    int col = nb + n * 16 + ln;
    float bb = b1[col];
#pragma unroll
    for (int m = 0; m < 4; ++m)
#pragma unroll
      for (int r = 0; r < 4; ++r) {
        int row = m * 16 + q * 4 + r;
        sT[row * 136 + col] = (f16)fmaxf(acc[m][n][r] + bb, 0.f);
      }
  }
  lds_barrier();

  f32x4 acc2[4][2];
#pragma unroll
  for (int m = 0; m < 4; ++m)
#pragma unroll
    for (int n = 0; n < 2; ++n) acc2[m][n] = 0.f;
#pragma unroll
  for (int k0 = 0; k0 < 128; k0 += 32) {
    f16x8 a[4];
#pragma unroll
    for (int m = 0; m < 4; ++m)
      a[m] = *(const f16x8*)&sT[(m * 16 + ln) * 136 + k0 + q * 8];
#pragma unroll
    for (int n = 0; n < 2; ++n) {
      f16x8 b = *(const f16x8*)&W2[(nb + n * 16 + ln) * 128 + k0 + q * 8];
#pragma unroll
      for (int m = 0; m < 4; ++m) acc2[m][n] = MFMA16(a[m], b, acc2[m][n]);
    }
  }
#pragma unroll
  for (int n = 0; n < 2; ++n) {
    int col = nb + n * 16 + ln;
    float bb = b2[col];
#pragma unroll
    for (int m = 0; m < 4; ++m)
#pragma unroll
      for (int r = 0; r < 4; ++r) {
        int row = m * 16 + q * 4 + r;
        int node = nbase + row;
        if (node < NN) n2[(size_t)node * 128 + col] = (f16)(acc2[m][n][r] + bb);
      }
  }
}

// ---------------- fused edge kernel (one layer) ----------------
// LAST UNPROBED QUADRANT: fewer waves + more registers.
// All prior register-pipelining failures (r1/r4/r5/r6/r9) moved along the
// SAME axis: more payload at >=4 waves/EU (128-reg budget, zero slack).
// This probe goes the other way: waves_per_eu(3,3) -> 512/3 = 170 regs/wave.
// Full depth-2 on BOTH gather streams: nearest-bin sets are 16 regs each,
// cur(32)+next(32)=64 payload + acc 32 + addressing ~25 = ~125 <= 170.
// Every st waits on loads issued ONE FULL PHASE earlier (mfma+st+barrier
// of cover vs one mfma_chunk now) -> attacks the convoy stall directly.
// Cost: 4 -> 3 blocks/CU (-25% TLP). Discriminators: VGPR_Count must jump
// >64 (budget opened); FETCH/WRITE stay ~67/94 MB (no spill). dur decides
// the occupancy-vs-depth trade; on regression revert to r10 k_edge and
// declare the structural plateau.

__global__ __launch_bounds__(256)
__attribute__((amdgpu_waves_per_eu(3, 3))) void k_edge(
    const int4* __restrict__ epack,
    const f16* __restrict__ T2, const f16* __restrict__ Dtab,
    const f16* __restrict__ We2b, const float* __restrict__ be2,
    const f16* __restrict__ Wcb, const float* __restrict__ bc,
    const f16* __restrict__ n2, float* __restrict__ h) {
  __shared__ __align__(16) f16 sC[2][64 * 136];  // K-chunk dbuf; sC[0]->n2, sC[1]->P
  __shared__ int sSrc[64], sDst[64], sT2o[64], sIdx[64];

  const int tid = threadIdx.x;
  const int e0 = blockIdx.x * 64;
  if (tid < 64) {
    int4 p = epack[e0 + tid];
    sSrc[tid] = p.x;
    sT2o[tid] = p.y;
    sIdx[tid] = p.z;
    sDst[tid] = p.w;
  }
  lds_barrier();

  const int lane = tid & 63, wave = tid >> 6;
  const int q = lane >> 4, ln = lane & 15;
  const int nb = wave * 32;

  f32x4 acc[4][2];
#pragma unroll
  for (int m = 0; m < 4; ++m)
#pragma unroll
    for (int n = 0; n < 2; ++n) acc[m][n] = 0.f;

  auto add_relu = [](f16x8 lo, f16x8 t2) -> f16x8 {
    f16x8 v = t2 + lo;
    f16x8 z = {};
    return __builtin_elementwise_max(v, z);
  };
  auto pfD128 = [&](int k0, f16x8* plo) {
    const int cg = tid & 15, eb = tid >> 4;
    const int col = k0 + cg * 8;
#pragma unroll
    for (int i = 0; i < 4; ++i)
      plo[i] = *(const f16x8*)&Dtab[sIdx[eb + i * 16] + col];
  };
  auto pfT128 = [&](int k0, f16x8* pt2) {
    const int cg = tid & 15, eb = tid >> 4;
    const int col = k0 + cg * 8;
#pragma unroll
    for (int i = 0; i < 4; ++i)
      pt2[i] = *(const f16x8*)&T2[sT2o[eb + i * 16] + col];
  };
  auto st128 = [&](f16* buf, const f16x8* plo, const f16x8* pt2) {
    const int cg = tid & 15, eb = tid >> 4;
#pragma unroll
    for (int i = 0; i < 4; ++i) {
      int e = eb + i * 16;
      *(f16x8*)&buf[e * 136 + cg * 8] = add_relu(plo[i], pt2[i]);
    }
  };
  auto pfD64 = [&](f16x8* plo) {
    const int cg = tid & 7, eb = tid >> 3;
    const int col = 384 + cg * 8;
#pragma unroll
    for (int i = 0; i < 2; ++i)
      plo[i] = *(const f16x8*)&Dtab[sIdx[eb + i * 32] + col];
  };
  auto pfT64 = [&](f16x8* pt2) {
    const int cg = tid & 7, eb = tid >> 3;
    const int col = 384 + cg * 8;
#pragma unroll
    for (int i = 0; i < 2; ++i)
      pt2[i] = *(const f16x8*)&T2[sT2o[eb + i * 32] + col];
  };
  auto st64 = [&](f16* buf, const f16x8* plo, const f16x8* pt2) {
    const int cg = tid & 7, eb = tid >> 3;
#pragma unroll
    for (int i = 0; i < 2; ++i) {
      int e = eb + i * 32;
      *(f16x8*)&buf[e * 136 + cg * 8] = add_relu(plo[i], pt2[i]);
    }
  };
  auto mfma_chunk = [&](const f16* buf, int k0, int nk) {
    for (int kk = 0; kk < nk; ++kk) {
      f16x8 a[4];
#pragma unroll
      for (int m = 0; m < 4; ++m)
        a[m] = *(const f16x8*)&buf[(m * 16 + ln) * 136 + kk * 32 + q * 8];
#pragma unroll
      for (int n = 0; n < 2; ++n) {
        f16x8 b = *(const f16x8*)&We2b[(nb + n * 16 + ln) * 448 + k0 + kk * 32 + q * 8];
#pragma unroll
        for (int m = 0; m < 4; ++m) acc[m][n] = MFMA16(a[m], b, acc[m][n]);
      }
    }
  };

  // ---- full depth-2 pipelined schedule (both streams) ----
  f16x8 dA[4], tA[4], dB[4], tB[4];
  f16x8 d64[2], t64[2];

  // prologue: chunk0 + chunk1 both in flight; stage chunk0
  pfD128(0, dA);
  pfT128(0, tA);
  pfD128(128, dB);
  pfT128(128, tB);
  st128(sC[0], dA, tA);
  lds_barrier();

  // phase 1: issue chunk2 into dA/tA; mfma chunk0; stage chunk1 (dB/tB,
  // issued a full phase ago)
  pfD128(256, dA);
  pfT128(256, tA);
  mfma_chunk(sC[0], 0, 4);
  st128(sC[1], dB, tB);
  lds_barrier();

  // phase 2: issue chunk3 (64-wide); mfma chunk1; stage chunk2 (dA/tA)
  pfD64(d64);
  pfT64(t64);
  mfma_chunk(sC[1], 128, 4);
  st128(sC[0], dA, tA);
  lds_barrier();

  // phase 3: n2 row gather; mfma chunk2; stage chunk3 (d64/t64)
  f16x8 nrows[4];  // u = tid + 256*i -> e=u>>4, cg=u&15
#pragma unroll
  for (int i = 0; i < 4; ++i) {
    int u = tid + 256 * i;
    int e = u >> 4, cg = u & 15;
    nrows[i] = *(const f16x8*)&n2[(size_t)sSrc[e] * 128 + cg * 8];
  }
  mfma_chunk(sC[0], 256, 4);
  st64(sC[1], d64, t64);
  lds_barrier();  // sC[0] now free for all waves

  // phase 4: write n2 rows to sN | mfma chunk3
  f16* sN = sC[0];
#pragma unroll
  for (int i = 0; i < 4; ++i) {
    int u = tid + 256 * i;
    int e = u >> 4, cg = u & 15;
    *(f16x8*)&sN[e * 136 + cg * 8] = nrows[i];
  }
  mfma_chunk(sC[1], 384, 2);
  lds_barrier();  // all waves done with sC[1]; reuse as P

  // epilogue 2: P = (EE + be2) * n2[src] -> sP (= sC[1])
  f16* sP = sC[1];
  {
    float be2v[2] = {be2[nb + ln], be2[nb + 16 + ln]};
#pragma unroll
    for (int n = 0; n < 2; ++n) {
      int col = nb + n * 16 + ln;
#pragma unroll
      for (int m = 0; m < 4; ++m)
#pragma unroll
        for (int r = 0; r < 4; ++r) {
          int row = m * 16 + q * 4 + r;
          float ee = acc[m][n][r] + be2v[n];
          sP[row * 136 + col] = (f16)(ee * (float)sN[row * 136 + col]);
        }
    }
  }
  lds_barrier();

  // phase 5: m = tanh(P @ Wc^T + bc); h[dst] += m  (run-merged atomics)
  {
    f32x4 acc2[4][2];
#pragma unroll
    for (int m = 0; m < 4; ++m)
#pragma unroll
      for (int n = 0; n < 2; ++n) acc2[m][n] = 0.f;
#pragma unroll
    for (int k0 = 0; k0 < 128; k0 += 32) {
      f16x8 a[4];
#pragma unroll
      for (int m = 0; m < 4; ++m)
        a[m] = *(const f16x8*)&sP[(m * 16 + ln) * 136 + k0 + q * 8];
#pragma unroll
      for (int n = 0; n < 2; ++n) {
        f16x8 b = *(const f16x8*)&Wcb[(nb + n * 16 + ln) * 128 + k0 + q * 8];
#pragma unroll
        for (int m = 0; m < 4; ++m) acc2[m][n] = MFMA16(a[m], b, acc2[m][n]);
      }
    }
    float bcv[2] = {bc[nb + ln], bc[nb + 16 + ln]};
#pragma unroll
    for (int m = 0; m < 4; ++m) {
      int d[4];
#pragma unroll
      for (int r = 0; r < 4; ++r) d[r] = sDst[m * 16 + q * 4 + r];
#pragma unroll
      for (int n = 0; n < 2; ++n) {
        int col = nb + n * 16 + ln;
        float tv[4];
#pragma unroll
        for (int r = 0; r < 4; ++r) {
          // Pade [3/2] tanh: inputs ~1e-3 scale, err << f16 ulp
          float x = acc2[m][n][r] + bcv[n];
          x = fminf(2.f, fmaxf(-2.f, x));
          float x2 = x * x;
          tv[r] = x * (15.f + x2) * __builtin_amdgcn_rcpf(15.f + 6.f * x2);
        }
        float s = tv[0];
        int cur = d[0];
#pragma unroll
        for (int r = 1; r < 4; ++r) {
          if (d[r] == cur) {
            s += tv[r];
          } else {
            unsafeAtomicAdd(&h[(size_t)cur * 128 + col], s);
            cur = d[r];
            s = tv[r];
          }
        }
        unsafeAtomicAdd(&h[(size_t)cur * 128 + col], s);
      }
    }
  }
}

// ---------------- readout ----------------

__global__ __launch_bounds__(256) void k_read(const float* __restrict__ h,
                                              const float* __restrict__ Wr1,
                                              const float* __restrict__ br1,
                                              const float* __restrict__ Wr2,
                                              const float* __restrict__ br2,
                                              const int* __restrict__ gid,
                                              float* __restrict__ out) {
  __shared__ __align__(16) f16 sH[64 * 136];
  __shared__ __align__(16) f16 sW[128 * 136];
  __shared__ float sR4[4][64];
  const int tid = threadIdx.x;
  const int nbase = blockIdx.x * 64;
  for (int i = tid; i < 64 * 32; i += 256) {
    int e = i >> 5, c = (i & 31) * 4;
    int node = nbase + e;
    float4 v = make_float4(0.f, 0.f, 0.f, 0.f);
    if (node < NN) v = *(const float4*)&h[(size_t)node * 128 + c];
    f16x4 o = {(f16)v.x, (f16)v.y, (f16)v.z, (f16)v.w};
    *(f16x4*)&sH[e * 136 + c] = o;
  }
  for (int i = tid; i < 128 * 32; i += 256) {
    int rr = i >> 5, c = (i & 31) * 4;
    float4 v = *(const float4*)&Wr1[rr * 128 + c];
    f16x4 o = {(f16)v.x, (f16)v.y, (f16)v.z, (f16)v.w};
    *(f16x4*)&sW[rr * 136 + c] = o;
  }
  lds_barrier();
  const int lane = tid & 63, wave = tid >> 6;
  const int q = lane >> 4, ln = lane & 15;
  const int nb = wave * 32;

  f32x4 acc[4][2];
#pragma unroll
  for (int m = 0; m < 4; ++m)
#pragma unroll
    for (int n = 0; n < 2; ++n) acc[m][n] = 0.f;
#pragma unroll
  for (int k0 = 0; k0 < 128; k0 += 32) {
    f16x8 a[4];
#pragma unroll
    for (int m = 0; m < 4; ++m)
      a[m] = *(const f16x8*)&sH[(m * 16 + ln) * 136 + k0 + q * 8];
#pragma unroll
    for (int n = 0; n < 2; ++n) {
      f16x8 b = *(const f16x8*)&sW[(nb + n * 16 + ln) * 136 + k0 + q * 8];
#pragma unroll
      for (int m = 0; m < 4; ++m) acc[m][n] = MFMA16(a[m], b, acc[m][n]);
    }
  }
#pragma unroll
  for (int m = 0; m < 4; ++m)
#pragma unroll
    for (int r = 0; r < 4; ++r) {
      float t = 0.f;
#pragma unroll
      for (int n = 0; n < 2; ++n) {
        int col = nb + n * 16 + ln;
        t += fmaxf(acc[m][n][r] + br1[col], 0.f) * Wr2[col];
      }
      t += __shfl_xor(t, 1);
      t += __shfl_xor(t, 2);
      t += __shfl_xor(t, 4);
      t += __shfl_xor(t, 8);
      if (ln == 0) sR4[wave][m * 16 + q * 4 + r] = t;
    }
  lds_barrier();
  if (tid < 64) {
    int node = nbase + tid;
    if (node < NN) {
      float s = sR4[0][tid] + sR4[1][tid] + sR4[2][tid] + sR4[3][tid] + br2[0];
      unsafeAtomicAdd(&out[gid[node]], s);
    }
  }
}

// ---------------- launch ----------------

extern "C" void kernel_launch(void* const* d_in, const int* in_sizes, int n_in,
                              void* d_out, int out_size, void* d_ws, size_t ws_size,
                              hipStream_t stream) {
  const int* Z = (const int*)d_in[0];
  const int* etype = (const int*)d_in[1];
  const float* dist = (const float*)d_in[2];
  const int* src = (const int*)d_in[3];
  const int* dst = (const int*)d_in[4];
  const int* gid = (const int*)d_in[5];
  const float* node_emb = (const float*)d_in[6];
  const float* edge_emb = (const float*)d_in[7];
  const float* Wn1 = (const float*)d_in[8];
  const float* bn1 = (const float*)d_in[9];
  const float* Wn2 = (const float*)d_in[10];
  const float* bn2 = (const float*)d_in[11];
  const float* We1 = (const float*)d_in[12];
  const float* be1 = (const float*)d_in[13];
  const float* We2 = (const float*)d_in[14];
  const float* be2 = (const float*)d_in[15];
  const float* Wc = (const float*)d_in[16];
  const float* bc = (const float*)d_in[17];
  const float* Wr1 = (const float*)d_in[18];
  const float* br1 = (const float*)d_in[19];
  const float* Wr2 = (const float*)d_in[20];
  const float* br2 = (const float*)d_in[21];
  float* out = (float*)d_out;

  char* ws = (char*)d_ws;
  float* h = (float*)(ws);                   // 51,200,000 B
  f16* n2 = (f16*)(ws + 51200000);           // 25,600,000 B
  f16* Rb = (f16*)(ws + 76800000);           //    860,160 B
  f16* We2b = (f16*)(ws + 77660160);         //    344,064 B
  f16* Wcb = (f16*)(ws + 78004224);          //     98,304 B
  f16* Wn1b = (f16*)(ws + 78102528);         //     98,304 B
  f16* Wn2b = (f16*)(ws + 78200832);         //     98,304 B
  f16* T2 = (f16*)(ws + 78299136);           //  1,075,200 B
  f16* Dtab = (f16*)(ws + 79374336);         //  5,507,712 B  -> 84,882,048
  int4* epack = (int4*)(ws + 84882048);      //  6,400,000 B  -> 91,282,048
  u32* hist = (u32*)(ws + 92882048);         //    400,000 B  -> 93,282,048
  u32* cursor = (u32*)(ws + 93282048);       //    400,000 B  -> 93,682,048
  u32* excl = (u32*)(ws + 93682048);         //    400,000 B  -> 94,082,048
  u32* part = (u32*)(ws + 94082048);         //        512 B  -> 94,082,560

  // prepw also zeroes hist (folded k_zero32)
  k_prepw<<<3319, 256, 0, stream>>>(Wn1, Wn2, Wc, We2, We1,
                                    Wn1b, Wn2b, Wcb, We2b, Rb, hist);
  // edge sort by dst (once, reused by all 3 layers)
  k_hist<<<1563, 256, 0, stream>>>(dst, hist);
  k_scan1<<<98, 1024, 0, stream>>>(hist, excl, part);
  k_scan3<<<98, 1024, 0, stream>>>(excl, part, cursor);  // scan2 folded in
  k_scatter<<<1563, 256, 0, stream>>>(etype, dist, src, dst, cursor, epack);

  k_t2<<<84, 256, 0, stream>>>(edge_emb, We1, be1, T2);
  k_dtab<<<3 * (GRID + 1), 256, 0, stream>>>(Rb, Dtab);

  for (int l = 0; l < 3; ++l) {
    if (l == 0) {
      k_node0<<<1563, 256, 0, stream>>>(Z, node_emb, Wn1b, bn1, Wn2b, bn2,
                                        n2, h, out);
    } else {
      k_node<<<1563, 256, 0, stream>>>(h, Wn1b + l * 16384, bn1 + l * 128,
                                       Wn2b + l * 16384, bn2 + l * 128, n2);
    }
    k_edge<<<6250, 256, 0, stream>>>(epack,
                                     T2 + l * 179200, Dtab + (size_t)l * (GRID + 1) * 448,
                                     We2b + l * 57344, be2 + l * 128,
                                     Wcb + l * 16384, bc + l * 128, n2, h);
  }
  k_read<<<1563, 256, 0, stream>>>(h, Wr1, br1, Wr2, br2, gid, out);
}

// Round 12
// 824.630 us; speedup vs baseline: 1.0580x; 1.0580x over previous
//
#include <hip/hip_runtime.h>

#define NN 100000
#define En 400000
#define Gn 2000
#define GRID 2048

typedef unsigned short u16;
typedef unsigned int u32;
typedef _Float16 f16;
typedef f16 f16x8 __attribute__((ext_vector_type(8)));
typedef f16 f16x4 __attribute__((ext_vector_type(4)));
typedef float f32x4 __attribute__((ext_vector_type(4)));

// barrier that drains only LDS ops (global loads/atomics stay in flight)
__device__ __forceinline__ void lds_barrier() {
  asm volatile("s_waitcnt lgkmcnt(0)\ns_barrier" ::: "memory");
}

#define MFMA16(a, b, c) __builtin_amdgcn_mfma_f32_16x16x32_f16(a, b, c, 0, 0, 0)

// ---------------- fused weight prep: converts + pads + hist zero ----------------

__global__ __launch_bounds__(256) void k_prepw(
    const float* __restrict__ Wn1, const float* __restrict__ Wn2,
    const float* __restrict__ Wc, const float* __restrict__ We2,
    const float* __restrict__ We1,
    f16* __restrict__ Wn1b, f16* __restrict__ Wn2b, f16* __restrict__ Wcb,
    f16* __restrict__ We2b, f16* __restrict__ Rb, u32* __restrict__ hist) {
  int i = blockIdx.x * 256 + threadIdx.x;
  if (i < 49152) {
    Wn1b[i] = (f16)Wn1[i];
  } else if (i < 98304) {
    int j = i - 49152;
    Wn2b[j] = (f16)Wn2[j];
  } else if (i < 147456) {
    int j = i - 98304;
    Wcb[j] = (f16)Wc[j];
  } else if (i < 319488) {
    int j = i - 147456;
    int l = j / 57344;
    int r = j - l * 57344;
    int row = r / 448;
    int k = r - row * 448;
    float v = (k < 428) ? We2[l * 54784 + row * 428 + k] : 0.f;
    We2b[j] = (f16)v;
  } else if (i < 749568) {
    int j = i - 319488;
    int l = j / 143360;
    int r = j - l * 143360;
    int row = r / 320;
    int k = r - row * 320;
    float v = 0.f;
    if (row < 428 && k < 300) v = We1[(size_t)l * 183184 + row * 428 + 128 + k];
    Rb[j] = (f16)v;
  } else if (i < 849568) {
    hist[i - 749568] = 0u;  // folded k_zero32
  }
}

// ---------------- T2 via MFMA ----------------
// T2[l][t][j] = edge_emb[t]·We1[l][j][:128] + be1[l][j]   f16 [3][400][448]

__global__ __launch_bounds__(256) void k_t2(const float* __restrict__ edge_emb,
                                            const float* __restrict__ We1,
                                            const float* __restrict__ be1,
                                            f16* __restrict__ T2) {
  __shared__ __align__(16) f16 sA[64 * 136];
  __shared__ __align__(16) f16 sB[128 * 136];
  const int tid = threadIdx.x;
  const int l = blockIdx.x / 28;
  const int rb = blockIdx.x - l * 28;
  const int tb = rb >> 2, jb = rb & 3;
  const int t0 = tb * 64, j0 = jb * 128;
  for (int i = tid; i < 64 * 32; i += 256) {
    int e = i >> 5, c = (i & 31) * 4;
    int t = t0 + e;
    float4 v = make_float4(0.f, 0.f, 0.f, 0.f);
    if (t < 400) v = *(const float4*)&edge_emb[t * 128 + c];
    f16x4 o = {(f16)v.x, (f16)v.y, (f16)v.z, (f16)v.w};
    *(f16x4*)&sA[e * 136 + c] = o;
  }
  for (int i = tid; i < 128 * 32; i += 256) {
    int rr = i >> 5, c = (i & 31) * 4;
    int j = j0 + rr;
    float4 v = make_float4(0.f, 0.f, 0.f, 0.f);
    if (j < 428) v = *(const float4*)&We1[(size_t)l * 183184 + j * 428 + c];
    f16x4 o = {(f16)v.x, (f16)v.y, (f16)v.z, (f16)v.w};
    *(f16x4*)&sB[rr * 136 + c] = o;
  }
  lds_barrier();
  const int lane = tid & 63, wave = tid >> 6;
  const int q = lane >> 4, ln = lane & 15;
  const int nb = wave * 32;

  f32x4 acc[4][2];
#pragma unroll
  for (int m = 0; m < 4; ++m)
#pragma unroll
    for (int n = 0; n < 2; ++n) acc[m][n] = 0.f;
#pragma unroll
  for (int k0 = 0; k0 < 128; k0 += 32) {
    f16x8 a[4];
#pragma unroll
    for (int m = 0; m < 4; ++m)
      a[m] = *(const f16x8*)&sA[(m * 16 + ln) * 136 + k0 + q * 8];
#pragma unroll
    for (int n = 0; n < 2; ++n) {
      f16x8 b = *(const f16x8*)&sB[(nb + n * 16 + ln) * 136 + k0 + q * 8];
#pragma unroll
      for (int m = 0; m < 4; ++m) acc[m][n] = MFMA16(a[m], b, acc[m][n]);
    }
  }
#pragma unroll
  for (int n = 0; n < 2; ++n) {
    int col = nb + n * 16 + ln;
    int gj = j0 + col;
    float bb = (gj < 428) ? be1[l * 428 + gj] : 0.f;
#pragma unroll
    for (int m = 0; m < 4; ++m)
#pragma unroll
      for (int r = 0; r < 4; ++r) {
        int row = m * 16 + q * 4 + r;
        int t = t0 + row;
        if (t < 400 && gj < 448) {
          float s = acc[m][n][r] + bb;
          T2[l * 179200 + t * 448 + gj] = (gj < 428) ? (f16)s : (f16)0.f;
        }
      }
  }
}

// Dtab[l][g][j] = sum_k rbf_k(g*delta) * R[l][j][k]   f16 [3][GRID+1][448]
// Vectorized: 5x f16x8 loads over an 8-aligned 40-tap window (vs 32 scalar
// f16 loads). Excluded far taps have weight <= exp(-25) ~ 1e-11.
__global__ __launch_bounds__(256) void k_dtab(const f16* __restrict__ Rb,
                                              f16* __restrict__ Dtab) {
  const int tid = threadIdx.x;
  int l = blockIdx.x / (GRID + 1);
  int g = blockIdx.x - l * (GRID + 1);
  float d = (float)g * (30.f / (float)GRID);
  int kc = (int)(d * (299.f / 30.f) + 0.5f);
  int kk0 = min(max(kc - 20, 0), 280) & ~7;
  __shared__ float sE[40];
  if (tid < 40) {
    float x = d - (float)(kk0 + tid) * (30.f / 299.f);
    sE[tid] = __expf(-x * x * (299.f / 30.f));
  }
  __syncthreads();
  for (int j = tid; j < 448; j += 256) {
    const f16* rr = &Rb[((size_t)l * 448 + j) * 320 + kk0];
    float s = 0.f;
#pragma unroll
    for (int v = 0; v < 5; ++v) {
      f16x8 rv = *(const f16x8*)&rr[v * 8];
#pragma unroll
      for (int t = 0; t < 8; ++t) s += sE[v * 8 + t] * (float)rv[t];
    }
    Dtab[((size_t)(l * (GRID + 1) + g)) * 448 + j] = (f16)s;
  }
}

// ---------------- counting sort of edges by dst ----------------

__global__ __launch_bounds__(256) void k_hist(const int* __restrict__ dstv,
                                              u32* __restrict__ hist) {
  int e = blockIdx.x * 256 + threadIdx.x;
  if (e < En) atomicAdd(&hist[dstv[e]], 1u);
}

// shfl-based block scan (2 barriers vs 20)
__global__ __launch_bounds__(1024) void k_scan1(const u32* __restrict__ hist,
                                                u32* __restrict__ excl,
                                                u32* __restrict__ part) {
  __shared__ u32 ws[16];
  const int t = threadIdx.x, b = blockIdx.x, i = b * 1024 + t;
  const int lane = t & 63, wid = t >> 6;
  u32 v = (i < NN) ? hist[i] : 0u;
  u32 acc = v;
#pragma unroll
  for (int off = 1; off < 64; off <<= 1) {
    u32 x = __shfl_up(acc, off);
    if (lane >= off) acc += x;
  }
  if (lane == 63) ws[wid] = acc;
  __syncthreads();
  if (t < 16) {
    u32 wa = ws[t];
#pragma unroll
    for (int off = 1; off < 16; off <<= 1) {
      u32 x = __shfl_up(wa, off);
      if (t >= off) wa += x;
    }
    ws[t] = wa;
  }
  __syncthreads();
  u32 base = (wid > 0) ? ws[wid - 1] : 0u;
  u32 inc = base + acc;
  if (i < NN) excl[i] = inc - v;
  if (t == 1023) part[b] = inc;
}

// scan3 with scan2 folded in: each block reduces part[0..b-1] itself
// (<=97 values, ~100 extra ops per block) -> one fewer kernel launch.
__global__ __launch_bounds__(1024) void k_scan3(const u32* __restrict__ excl,
                                                const u32* __restrict__ part,
                                                u32* __restrict__ cursor) {
  __shared__ u32 sW[2];
  __shared__ u32 sBase;
  const int t = threadIdx.x, b = blockIdx.x;
  if (t < 128) {
    u32 v = (t < b) ? part[t] : 0u;  // b <= 97 < 128
#pragma unroll
    for (int off = 32; off > 0; off >>= 1) v += __shfl_down(v, off);
    if ((t & 63) == 0) sW[t >> 6] = v;
  }
  __syncthreads();
  if (t == 0) sBase = sW[0] + sW[1];
  __syncthreads();
  int i = b * 1024 + t;
  if (i < NN) cursor[i] = excl[i] + sBase;
}

// nearest-bin index (r8); dst packed into epack.w (edst array eliminated).
// fi < 2048 -> round(fi) <= 2048; Dtab has GRID+1 = 2049 rows -> in range.
__global__ __launch_bounds__(256) void k_scatter(const int* __restrict__ etype,
                                                 const float* __restrict__ dist,
                                                 const int* __restrict__ srcv,
                                                 const int* __restrict__ dstv,
                                                 u32* __restrict__ cursor,
                                                 int4* __restrict__ epack) {
  int e = blockIdx.x * 256 + threadIdx.x;
  if (e >= En) return;
  int d = dstv[e];
  int pos = (int)atomicAdd(&cursor[d], 1u);
  float fi = dist[e] * ((float)GRID / 30.f);
  int ix = (int)(fi + 0.5f);
  epack[pos] = make_int4(srcv[e], etype[e] * 448, ix * 448, d);
}

// ---------------- node MLP: n2 = relu(h@W1^T+b1)@W2^T+b2  (f16 out) ----------------

__global__ __launch_bounds__(256) void k_node(const float* __restrict__ h,
                                              const f16* __restrict__ W1,
                                              const float* __restrict__ b1,
                                              const f16* __restrict__ W2,
                                              const float* __restrict__ b2,
                                              f16* __restrict__ n2) {
  __shared__ __align__(16) f16 sH[64 * 136];
  __shared__ __align__(16) f16 sT[64 * 136];
  const int tid = threadIdx.x;
  const int nbase = blockIdx.x * 64;
  for (int i = tid; i < 64 * 32; i += 256) {
    int e = i >> 5, c = (i & 31) * 4;
    int node = nbase + e;
    float4 v = make_float4(0.f, 0.f, 0.f, 0.f);
    if (node < NN) v = *(const float4*)&h[(size_t)node * 128 + c];
    f16x4 o = {(f16)v.x, (f16)v.y, (f16)v.z, (f16)v.w};
    *(f16x4*)&sH[e * 136 + c] = o;
  }
  lds_barrier();
  const int lane = tid & 63, wave = tid >> 6;
  const int q = lane >> 4, ln = lane & 15;
  const int nb = wave * 32;

  f32x4 acc[4][2];
#pragma unroll
  for (int m = 0; m < 4; ++m)
#pragma unroll
    for (int n = 0; n < 2; ++n) acc[m][n] = 0.f;
#pragma unroll
  for (int k0 = 0; k0 < 128; k0 += 32) {
    f16x8 a[4];
#pragma unroll
    for (int m = 0; m < 4; ++m)
      a[m] = *(const f16x8*)&sH[(m * 16 + ln) * 136 + k0 + q * 8];
#pragma unroll
    for (int n = 0; n < 2; ++n) {
      f16x8 b = *(const f16x8*)&W1[(nb + n * 16 + ln) * 128 + k0 + q * 8];
#pragma unroll
      for (int m = 0; m < 4; ++m) acc[m][n] = MFMA16(a[m], b, acc[m][n]);
    }
  }
#pragma unroll
  for (int n = 0; n < 2; ++n) {
    int col = nb + n * 16 + ln;
    float bb = b1[col];
#pragma unroll
    for (int m = 0; m < 4; ++m)
#pragma unroll
      for (int r = 0; r < 4; ++r) {
        int row = m * 16 + q * 4 + r;
        sT[row * 136 + col] = (f16)fmaxf(acc[m][n][r] + bb, 0.f);
      }
  }
  lds_barrier();

  f32x4 acc2[4][2];
#pragma unroll
  for (int m = 0; m < 4; ++m)
#pragma unroll
    for (int n = 0; n < 2; ++n) acc2[m][n] = 0.f;
#pragma unroll
  for (int k0 = 0; k0 < 128; k0 += 32) {
    f16x8 a[4];
#pragma unroll
    for (int m = 0; m < 4; ++m)
      a[m] = *(const f16x8*)&sT[(m * 16 + ln) * 136 + k0 + q * 8];
#pragma unroll
    for (int n = 0; n < 2; ++n) {
      f16x8 b = *(const f16x8*)&W2[(nb + n * 16 + ln) * 128 + k0 + q * 8];
#pragma unroll
      for (int m = 0; m < 4; ++m) acc2[m][n] = MFMA16(a[m], b, acc2[m][n]);
    }
  }
#pragma unroll
  for (int n = 0; n < 2; ++n) {
    int col = nb + n * 16 + ln;
    float bb = b2[col];
#pragma unroll
    for (int m = 0; m < 4; ++m)
#pragma unroll
      for (int r = 0; r < 4; ++r) {
        int row = m * 16 + q * 4 + r;
        int node = nbase + row;
        if (node < NN) n2[(size_t)node * 128 + col] = (f16)(acc2[m][n][r] + bb);
      }
  }
}

// ---------------- layer-0 node MLP fused with h-init ----------------

__global__ __launch_bounds__(256) void k_node0(const int* __restrict__ Z,
                                               const float* __restrict__ node_emb,
                                               const f16* __restrict__ W1,
                                               const float* __restrict__ b1,
                                               const f16* __restrict__ W2,
                                               const float* __restrict__ b2,
                                               f16* __restrict__ n2,
                                               float* __restrict__ h,
                                               float* __restrict__ out) {
  __shared__ __align__(16) f16 sH[64 * 136];
  __shared__ __align__(16) f16 sT[64 * 136];
  __shared__ int sZ[64];
  const int tid = threadIdx.x;
  const int nbase = blockIdx.x * 64;
  {
    int oi = blockIdx.x * 256 + tid;
    if (oi < Gn) out[oi] = 0.f;
  }
  if (tid < 64) sZ[tid] = Z[min(nbase + tid, NN - 1)];
  lds_barrier();
  for (int i = tid; i < 64 * 32; i += 256) {
    int e = i >> 5, c = (i & 31) * 4;
    int node = nbase + e;
    float4 v = *(const float4*)&node_emb[sZ[e] * 128 + c];
    f16x4 o = {(f16)v.x, (f16)v.y, (f16)v.z, (f16)v.w};
    *(f16x4*)&sH[e * 136 + c] = o;
    if (node < NN) *(float4*)&h[(size_t)node * 128 + c] = v;
  }
  lds_barrier();
  const int lane = tid & 63, wave = tid >> 6;
  const int q = lane >> 4, ln = lane & 15;
  const int nb = wave * 32;

  f32x4 acc[4][2];
#pragma unroll
  for (int m = 0; m < 4; ++m)
#pragma unroll
    for (int n = 0; n < 2; ++n) acc[m][n] = 0.f;
#pragma unroll
  for (int k0 = 0; k0 < 128; k0 += 32) {
    f16x8 a[4];
#pragma unroll
    for (int m = 0; m < 4; ++m)
      a[m] = *(const f16x8*)&sH[(m * 16 + ln) * 136 + k0 + q * 8];
#pragma unroll
    for (int n = 0; n < 2; ++n) {
      f16x8 b = *(const f16x8*)&W1[(nb + n * 16 + ln) * 128 + k0 + q * 8];
#pragma unroll
      for (int m = 0; m < 4; ++m) acc[m][n] = MFMA16(a[m], b, acc[m][n]);
    }
  }
#pragma unroll
  for (int n = 0; n < 2; ++n) {
    int col = nb + n * 16 + ln;
    float bb = b1[col];
#pragma unroll
    for (int m = 0; m < 4; ++m)
#pragma unroll
      for (int r = 0; r < 4; ++r) {
        int row = m * 16 + q * 4 + r;
        sT[row * 136 + col] = (f16)fmaxf(acc[m][n][r] + bb, 0.f);
      }
  }
  lds_barrier();

  f32x4 acc2[4][2];
#pragma unroll
  for (int m = 0; m < 4; ++m)
#pragma unroll
    for (int n = 0; n < 2; ++n) acc2[m][n] = 0.f;
#pragma unroll
  for (int k0 = 0; k0 < 128; k0 += 32) {
    f16x8 a[4];
#pragma unroll
    for (int m = 0; m < 4; ++m)
      a[m] = *(const f16x8*)&sT[(m * 16 + ln) * 136 + k0 + q * 8];
#pragma unroll
    for (int n = 0; n < 2; ++n) {
      f16x8 b = *(const f16x8*)&W2[(nb + n * 16 + ln) * 128 + k0 + q * 8];
#pragma unroll
      for (int m = 0; m < 4; ++m) acc2[m][n] = MFMA16(a[m], b, acc2[m][n]);
    }
  }
#pragma unroll
  for (int n = 0; n < 2; ++n) {
    int col = nb + n * 16 + ln;
    float bb = b2[col];
#pragma unroll
    for (int m = 0; m < 4; ++m)
#pragma unroll
      for (int r = 0; r < 4; ++r) {
        int row = m * 16 + q * 4 + r;
        int node = nbase + row;
        if (node < NN) n2[(size_t)node * 128 + col] = (f16)(acc2[m][n][r] + bb);
      }
  }
}

// ---------------- fused edge kernel (one layer) ----------------
// r10 BEST form (828.9 us total; k_edge 170.3 us, VGPR 64, Occ 41.4,
// FETCH 67.3 MB, WRITE 94.2 MB, no spill). Structural local optimum.
// COMPLETE probe ledger (all closed, DO NOT revisit):
//  r1  occupancy 8blk/CU (64-wide chunks, waves 6-8): VGPR starvation
//  r2  barrier-free wave-private edges: gather latency fully exposed
//  r3  XCD-chunked swizzle: exact no-op on every counter
//  r4/r5 depth-2/3-set reg prefetch @128-reg budget: scratch spills
//  r6  s_setprio graft: regalloc perturbation -> spills
//  r9  depth-2-lite (+16 regs): mild spill == latency gain (neutral)
//  r11 depth-2 @ waves_per_eu(3,3)/170 regs: compiler serializes the
//      prefetch sets anyway (VGPR only 72); -25% occupancy costs 13 us
// Mechanism: 4-wave lockstep convoy on L2-return of the gather streams,
// with zero register slack at the occupancy that hides the most latency.

__global__ __launch_bounds__(256)
__attribute__((amdgpu_waves_per_eu(4, 4))) void k_edge(
    const int4* __restrict__ epack,
    const f16* __restrict__ T2, const f16* __restrict__ Dtab,
    const f16* __restrict__ We2b, const float* __restrict__ be2,
    const f16* __restrict__ Wcb, const float* __restrict__ bc,
    const f16* __restrict__ n2, float* __restrict__ h) {
  __shared__ __align__(16) f16 sC[2][64 * 136];  // K-chunk dbuf; sC[0]->n2, sC[1]->P
  __shared__ int sSrc[64], sDst[64], sT2o[64], sIdx[64];

  const int tid = threadIdx.x;
  const int e0 = blockIdx.x * 64;
  if (tid < 64) {
    int4 p = epack[e0 + tid];
    sSrc[tid] = p.x;
    sT2o[tid] = p.y;
    sIdx[tid] = p.z;
    sDst[tid] = p.w;
  }
  lds_barrier();

  const int lane = tid & 63, wave = tid >> 6;
  const int q = lane >> 4, ln = lane & 15;
  const int nb = wave * 32;

  f32x4 acc[4][2];
#pragma unroll
  for (int m = 0; m < 4; ++m)
#pragma unroll
    for (int n = 0; n < 2; ++n) acc[m][n] = 0.f;

  auto add_relu = [](f16x8 lo, f16x8 t2) -> f16x8 {
    f16x8 v = t2 + lo;
    f16x8 z = {};
    return __builtin_elementwise_max(v, z);
  };
  auto pf128 = [&](int k0, f16x8* plo, f16x8* pt2) {
    const int cg = tid & 15, eb = tid >> 4;
    const int col = k0 + cg * 8;
#pragma unroll
    for (int i = 0; i < 4; ++i) {
      int e = eb + i * 16;
      plo[i] = *(const f16x8*)&Dtab[sIdx[e] + col];
      pt2[i] = *(const f16x8*)&T2[sT2o[e] + col];
    }
  };
  auto st128 = [&](f16* buf, const f16x8* plo, const f16x8* pt2) {
    const int cg = tid & 15, eb = tid >> 4;
#pragma unroll
    for (int i = 0; i < 4; ++i) {
      int e = eb + i * 16;
      *(f16x8*)&buf[e * 136 + cg * 8] = add_relu(plo[i], pt2[i]);
    }
  };
  auto pf64 = [&](f16x8* plo, f16x8* pt2) {
    const int cg = tid & 7, eb = tid >> 3;
    const int col = 384 + cg * 8;
#pragma unroll
    for (int i = 0; i < 2; ++i) {
      int e = eb + i * 32;
      plo[i] = *(const f16x8*)&Dtab[sIdx[e] + col];
      pt2[i] = *(const f16x8*)&T2[sT2o[e] + col];
    }
  };
  auto st64 = [&](f16* buf, const f16x8* plo, const f16x8* pt2) {
    const int cg = tid & 7, eb = tid >> 3;
#pragma unroll
    for (int i = 0; i < 2; ++i) {
      int e = eb + i * 32;
      *(f16x8*)&buf[e * 136 + cg * 8] = add_relu(plo[i], pt2[i]);
    }
  };
  auto mfma_chunk = [&](const f16* buf, int k0, int nk) {
    for (int kk = 0; kk < nk; ++kk) {
      f16x8 a[4];
#pragma unroll
      for (int m = 0; m < 4; ++m)
        a[m] = *(const f16x8*)&buf[(m * 16 + ln) * 136 + kk * 32 + q * 8];
#pragma unroll
      for (int n = 0; n < 2; ++n) {
        f16x8 b = *(const f16x8*)&We2b[(nb + n * 16 + ln) * 448 + k0 + kk * 32 + q * 8];
#pragma unroll
        for (int m = 0; m < 4; ++m) acc[m][n] = MFMA16(a[m], b, acc[m][n]);
      }
    }
  };

  // pipelined chunk schedule (r8 exact)
  {
    f16x8 plo[4], pt2[4];
    pf128(0, plo, pt2);
    st128(sC[0], plo, pt2);
  }
  lds_barrier();
  {
    f16x8 plo[4], pt2[4];
    pf128(128, plo, pt2);
    mfma_chunk(sC[0], 0, 4);
    st128(sC[1], plo, pt2);
  }
  lds_barrier();
  {
    f16x8 plo[4], pt2[4];
    pf128(256, plo, pt2);
    mfma_chunk(sC[1], 128, 4);
    st128(sC[0], plo, pt2);
  }
  lds_barrier();
  f16x8 nrows[4];  // n2 row staging: u = tid + 256*i -> e=u>>4, cg=u&15
  {
    f16x8 plo[2], pt2[2];
    pf64(plo, pt2);
#pragma unroll
    for (int i = 0; i < 4; ++i) {
      int u = tid + 256 * i;
      int e = u >> 4, cg = u & 15;
      nrows[i] = *(const f16x8*)&n2[(size_t)sSrc[e] * 128 + cg * 8];
    }
    mfma_chunk(sC[0], 256, 4);
    st64(sC[1], plo, pt2);
  }
  lds_barrier();  // sC[0] now free for all waves

  f16* sN = sC[0];
#pragma unroll
  for (int i = 0; i < 4; ++i) {
    int u = tid + 256 * i;
    int e = u >> 4, cg = u & 15;
    *(f16x8*)&sN[e * 136 + cg * 8] = nrows[i];
  }
  mfma_chunk(sC[1], 384, 2);
  lds_barrier();  // all waves done with sC[1]; reuse as P

  // epilogue 2: P = (EE + be2) * n2[src] -> sP (= sC[1])
  f16* sP = sC[1];
  {
    float be2v[2] = {be2[nb + ln], be2[nb + 16 + ln]};
#pragma unroll
    for (int n = 0; n < 2; ++n) {
      int col = nb + n * 16 + ln;
#pragma unroll
      for (int m = 0; m < 4; ++m)
#pragma unroll
        for (int r = 0; r < 4; ++r) {
          int row = m * 16 + q * 4 + r;
          float ee = acc[m][n][r] + be2v[n];
          sP[row * 136 + col] = (f16)(ee * (float)sN[row * 136 + col]);
        }
    }
  }
  lds_barrier();

  // phase 3: m = tanh(P @ Wc^T + bc); h[dst] += m  (run-merged atomics)
  {
    f32x4 acc2[4][2];
#pragma unroll
    for (int m = 0; m < 4; ++m)
#pragma unroll
      for (int n = 0; n < 2; ++n) acc2[m][n] = 0.f;
#pragma unroll
    for (int k0 = 0; k0 < 128; k0 += 32) {
      f16x8 a[4];
#pragma unroll
      for (int m = 0; m < 4; ++m)
        a[m] = *(const f16x8*)&sP[(m * 16 + ln) * 136 + k0 + q * 8];
#pragma unroll
      for (int n = 0; n < 2; ++n) {
        f16x8 b = *(const f16x8*)&Wcb[(nb + n * 16 + ln) * 128 + k0 + q * 8];
#pragma unroll
        for (int m = 0; m < 4; ++m) acc2[m][n] = MFMA16(a[m], b, acc2[m][n]);
      }
    }
    float bcv[2] = {bc[nb + ln], bc[nb + 16 + ln]};
#pragma unroll
    for (int m = 0; m < 4; ++m) {
      int d[4];
#pragma unroll
      for (int r = 0; r < 4; ++r) d[r] = sDst[m * 16 + q * 4 + r];
#pragma unroll
      for (int n = 0; n < 2; ++n) {
        int col = nb + n * 16 + ln;
        float tv[4];
#pragma unroll
        for (int r = 0; r < 4; ++r) {
          // Pade [3/2] tanh: inputs ~1e-3 scale, err << f16 ulp
          float x = acc2[m][n][r] + bcv[n];
          x = fminf(2.f, fmaxf(-2.f, x));
          float x2 = x * x;
          tv[r] = x * (15.f + x2) * __builtin_amdgcn_rcpf(15.f + 6.f * x2);
        }
        float s = tv[0];
        int cur = d[0];
#pragma unroll
        for (int r = 1; r < 4; ++r) {
          if (d[r] == cur) {
            s += tv[r];
          } else {
            unsafeAtomicAdd(&h[(size_t)cur * 128 + col], s);
            cur = d[r];
            s = tv[r];
          }
        }
        unsafeAtomicAdd(&h[(size_t)cur * 128 + col], s);
      }
    }
  }
}

// ---------------- readout ----------------

__global__ __launch_bounds__(256) void k_read(const float* __restrict__ h,
                                              const float* __restrict__ Wr1,
                                              const float* __restrict__ br1,
                                              const float* __restrict__ Wr2,
                                              const float* __restrict__ br2,
                                              const int* __restrict__ gid,
                                              float* __restrict__ out) {
  __shared__ __align__(16) f16 sH[64 * 136];
  __shared__ __align__(16) f16 sW[128 * 136];
  __shared__ float sR4[4][64];
  const int tid = threadIdx.x;
  const int nbase = blockIdx.x * 64;
  for (int i = tid; i < 64 * 32; i += 256) {
    int e = i >> 5, c = (i & 31) * 4;
    int node = nbase + e;
    float4 v = make_float4(0.f, 0.f, 0.f, 0.f);
    if (node < NN) v = *(const float4*)&h[(size_t)node * 128 + c];
    f16x4 o = {(f16)v.x, (f16)v.y, (f16)v.z, (f16)v.w};
    *(f16x4*)&sH[e * 136 + c] = o;
  }
  for (int i = tid; i < 128 * 32; i += 256) {
    int rr = i >> 5, c = (i & 31) * 4;
    float4 v = *(const float4*)&Wr1[rr * 128 + c];
    f16x4 o = {(f16)v.x, (f16)v.y, (f16)v.z, (f16)v.w};
    *(f16x4*)&sW[rr * 136 + c] = o;
  }
  lds_barrier();
  const int lane = tid & 63, wave = tid >> 6;
  const int q = lane >> 4, ln = lane & 15;
  const int nb = wave * 32;

  f32x4 acc[4][2];
#pragma unroll
  for (int m = 0; m < 4; ++m)
#pragma unroll
    for (int n = 0; n < 2; ++n) acc[m][n] = 0.f;
#pragma unroll
  for (int k0 = 0; k0 < 128; k0 += 32) {
    f16x8 a[4];
#pragma unroll
    for (int m = 0; m < 4; ++m)
      a[m] = *(const f16x8*)&sH[(m * 16 + ln) * 136 + k0 + q * 8];
#pragma unroll
    for (int n = 0; n < 2; ++n) {
      f16x8 b = *(const f16x8*)&sW[(nb + n * 16 + ln) * 136 + k0 + q * 8];
#pragma unroll
      for (int m = 0; m < 4; ++m) acc[m][n] = MFMA16(a[m], b, acc[m][n]);
    }
  }
#pragma unroll
  for (int m = 0; m < 4; ++m)
#pragma unroll
    for (int r = 0; r < 4; ++r) {
      float t = 0.f;
#pragma unroll
      for (int n = 0; n < 2; ++n) {
        int col = nb + n * 16 + ln;
        t += fmaxf(acc[m][n][r] + br1[col], 0.f) * Wr2[col];
      }
      t += __shfl_xor(t, 1);
      t += __shfl_xor(t, 2);
      t += __shfl_xor(t, 4);
      t += __shfl_xor(t, 8);
      if (ln == 0) sR4[wave][m * 16 + q * 4 + r] = t;
    }
  lds_barrier();
  if (tid < 64) {
    int node = nbase + tid;
    if (node < NN) {
      float s = sR4[0][tid] + sR4[1][tid] + sR4[2][tid] + sR4[3][tid] + br2[0];
      unsafeAtomicAdd(&out[gid[node]], s);
    }
  }
}

// ---------------- launch ----------------

extern "C" void kernel_launch(void* const* d_in, const int* in_sizes, int n_in,
                              void* d_out, int out_size, void* d_ws, size_t ws_size,
                              hipStream_t stream) {
  const int* Z = (const int*)d_in[0];
  const int* etype = (const int*)d_in[1];
  const float* dist = (const float*)d_in[2];
  const int* src = (const int*)d_in[3];
  const int* dst = (const int*)d_in[4];
  const int* gid = (const int*)d_in[5];
  const float* node_emb = (const float*)d_in[6];
  const float* edge_emb = (const float*)d_in[7];
  const float* Wn1 = (const float*)d_in[8];
  const float* bn1 = (const float*)d_in[9];
  const float* Wn2 = (const float*)d_in[10];
  const float* bn2 = (const float*)d_in[11];
  const float* We1 = (const float*)d_in[12];
  const float* be1 = (const float*)d_in[13];
  const float* We2 = (const float*)d_in[14];
  const float* be2 = (const float*)d_in[15];
  const float* Wc = (const float*)d_in[16];
  const float* bc = (const float*)d_in[17];
  const float* Wr1 = (const float*)d_in[18];
  const float* br1 = (const float*)d_in[19];
  const float* Wr2 = (const float*)d_in[20];
  const float* br2 = (const float*)d_in[21];
  float* out = (float*)d_out;

  char* ws = (char*)d_ws;
  float* h = (float*)(ws);                   // 51,200,000 B
  f16* n2 = (f16*)(ws + 51200000);           // 25,600,000 B
  f16* Rb = (f16*)(ws + 76800000);           //    860,160 B
  f16* We2b = (f16*)(ws + 77660160);         //    344,064 B
  f16* Wcb = (f16*)(ws + 78004224);          //     98,304 B
  f16* Wn1b = (f16*)(ws + 78102528);         //     98,304 B
  f16* Wn2b = (f16*)(ws + 78200832);         //     98,304 B
  f16* T2 = (f16*)(ws + 78299136);           //  1,075,200 B
  f16* Dtab = (f16*)(ws + 79374336);         //  5,507,712 B  -> 84,882,048
  int4* epack = (int4*)(ws + 84882048);      //  6,400,000 B  -> 91,282,048
  u32* hist = (u32*)(ws + 92882048);         //    400,000 B  -> 93,282,048
  u32* cursor = (u32*)(ws + 93282048);       //    400,000 B  -> 93,682,048
  u32* excl = (u32*)(ws + 93682048);         //    400,000 B  -> 94,082,048
  u32* part = (u32*)(ws + 94082048);         //        512 B  -> 94,082,560

  // prepw also zeroes hist (folded k_zero32)
  k_prepw<<<3319, 256, 0, stream>>>(Wn1, Wn2, Wc, We2, We1,
                                    Wn1b, Wn2b, Wcb, We2b, Rb, hist);
  // edge sort by dst (once, reused by all 3 layers)
  k_hist<<<1563, 256, 0, stream>>>(dst, hist);
  k_scan1<<<98, 1024, 0, stream>>>(hist, excl, part);
  k_scan3<<<98, 1024, 0, stream>>>(excl, part, cursor);  // scan2 folded in
  k_scatter<<<1563, 256, 0, stream>>>(etype, dist, src, dst, cursor, epack);

  k_t2<<<84, 256, 0, stream>>>(edge_emb, We1, be1, T2);
  k_dtab<<<3 * (GRID + 1), 256, 0, stream>>>(Rb, Dtab);

  for (int l = 0; l < 3; ++l) {
    if (l == 0) {
      k_node0<<<1563, 256, 0, stream>>>(Z, node_emb, Wn1b, bn1, Wn2b, bn2,
                                        n2, h, out);
    } else {
      k_node<<<1563, 256, 0, stream>>>(h, Wn1b + l * 16384, bn1 + l * 128,
                                       Wn2b + l * 16384, bn2 + l * 128, n2);
    }
    k_edge<<<6250, 256, 0, stream>>>(epack,
                                     T2 + l * 179200, Dtab + (size_t)l * (GRID + 1) * 448,
                                     We2b + l * 57344, be2 + l * 128,
                                     Wcb + l * 16384, bc + l * 128, n2, h);
  }
  k_read<<<1563, 256, 0, stream>>>(h, Wr1, br1, Wr2, br2, gid, out);
}